// Round 12
// baseline (37.209 us; speedup 1.0000x reference)
//
#include <hip/hip_runtime.h>

#define NROW 128
#define NZ   8128      // 128*127/2
#define EPSF 1e-12f
#define RPW  8         // rows per unit

typedef float vfloat2 __attribute__((ext_vector_type(2)));  // native vec for nt-store

// R11 math + PERSISTENT WAVES: grid = B blocks (8 blocks/CU, all resident),
// each wave processes 4 independent 8-row units, software-pipelined 2 deep
// (loads of unit n+1 issued before compute of unit n). Motivation: each wave
// retire pays an s_waitcnt vmcnt(0) drain for its NT stores; 4 units/wave
// divides that fixed cost by 4 and removes wave-slot churn.
//
// Per row, lane l owns elements {2l, 2l+1} (one dwordx2 load, one NT dwordx2
// store, both 512B-contiguous per wave). Closed form (telescoped scan):
//   1 - s_j = prod_{k<j}(1 - z_k^2)
//   L[i,j] = z[i,j]*sqrt(max(P_j,EPS)) (j<i), L[i,i]=sqrt(max(P_i,EPS)), 0 above.
// Full 64-lane multiplicative scan in 6 DPP muls (validated R4/R7/R10/R11).
// Load clamp min(base+2l, NZ-2) displaces only (i=127,lane63): there zA=v.y
// (selected) and zB is dead (p1==i -> diagonal path).
#define DPP_MUL(x, ctrl, rmask)                                               \
  x *= __int_as_float(__builtin_amdgcn_update_dpp(                            \
      0x3f800000, __float_as_int(x), ctrl, rmask, 0xF, false))

__device__ __forceinline__ void load_unit(const float* __restrict__ z, int unit,
                                          int p0, float* zA, float* zB)
{
    const int row0 = unit * RPW;
    const int b    = row0 >> 7;
    const float* __restrict__ zb = z + (size_t)b * NZ;
    #pragma unroll
    for (int k = 0; k < RPW; ++k) {
        const int i    = (row0 + k) & 127;
        const int base = (i * (i - 1)) >> 1;
        const int ap   = base + p0;
        const int a    = min(ap, NZ - 2);          // shifts only (i=127, lane63)
        const float2 v = *reinterpret_cast<const float2*>(zb + a);
        zA[k] = (ap > a) ? v.y : v.x;              // shifted lane: live elem is .y
        zB[k] = v.y;                               // garbage iff shifted -> dead
    }
}

__device__ __forceinline__ void comp_unit(float* __restrict__ out, int unit,
                                          int p0, int p1,
                                          const float* zA, const float* zB)
{
    const int row0 = unit * RPW;
    #pragma unroll
    for (int k = 0; k < RPW; ++k) {
        const int  i  = (row0 + k) & 127;
        const bool m0 = (p0 < i);
        const bool m1 = (p1 < i);
        const float z0 = zA[k], z1 = zB[k];

        const float f0   = m0 ? fmaf(-z0, z0, 1.0f) : 1.0f;
        const float f1   = m1 ? fmaf(-z1, z1, 1.0f) : 1.0f;
        const float pair = f0 * f1;

        // Inclusive 64-lane multiplicative scan of pair (6 DPP muls)
        float x = pair;
        DPP_MUL(x, 0x111, 0xF);   // row_shr:1
        DPP_MUL(x, 0x112, 0xF);   // row_shr:2
        DPP_MUL(x, 0x114, 0xF);   // row_shr:4
        DPP_MUL(x, 0x118, 0xF);   // row_shr:8
        DPP_MUL(x, 0x142, 0xA);   // row_bcast:15 -> rows 1,3
        DPP_MUL(x, 0x143, 0xC);   // row_bcast:31 -> rows 2,3

        // Exclusive prefix: e = x / pair (pair >= 0.036 for |z|<=0.9; masked = 1)
        const float e    = x * __builtin_amdgcn_rcpf(pair);
        const float pre1 = e * f0;

        const float sq0 = __builtin_amdgcn_sqrtf(fmaxf(e,    EPSF));
        const float sq1 = __builtin_amdgcn_sqrtf(fmaxf(pre1, EPSF));

        const float o0 = m0 ? z0 * sq0 : ((p0 == i) ? sq0 : 0.0f);
        const float o1 = m1 ? z1 * sq1 : ((p1 == i) ? sq1 : 0.0f);

        // Nontemporal aligned 8B store (row base 512B-aligned, +8B*lane)
        vfloat2 v; v.x = o0; v.y = o1;
        vfloat2* dst = reinterpret_cast<vfloat2*>(out + (size_t)(row0 + k) * NROW + p0);
        __builtin_nontemporal_store(v, dst);
    }
}

__global__ __launch_bounds__(256, 8) void chol_from_z_kernel(
    const float* __restrict__ z, float* __restrict__ out, int gw)
{
    const int gtid = blockIdx.x * blockDim.x + threadIdx.x;
    const int w    = gtid >> 6;            // persistent wave id, w in [0, gw)
    const int lane = threadIdx.x & 63;
    const int p0   = lane << 1;
    const int p1   = p0 | 1;

    // 4 units per wave: {w, w+gw, w+2gw, w+3gw}; 2-deep pipeline.
    float a0[RPW], b0[RPW], a1[RPW], b1[RPW];

    load_unit(z, w,          p0, a0, b0);
    load_unit(z, w + gw,     p0, a1, b1);
    comp_unit(out, w,        p0, p1, a0, b0);
    load_unit(z, w + 2 * gw, p0, a0, b0);
    comp_unit(out, w + gw,   p0, p1, a1, b1);
    load_unit(z, w + 3 * gw, p0, a1, b1);
    comp_unit(out, w + 2*gw, p0, p1, a0, b0);
    comp_unit(out, w + 3*gw, p0, p1, a1, b1);
}

extern "C" void kernel_launch(void* const* d_in, const int* in_sizes, int n_in,
                              void* d_out, int out_size, void* d_ws, size_t ws_size,
                              hipStream_t stream)
{
    const float* z = (const float*)d_in[0];
    float* out = (float*)d_out;

    const int B = in_sizes[0] / NZ;          // 2048
    const int nunits = B * NROW / RPW;       // 32768 (16 units per batch)
    const int gw = nunits / 4;               // 8192 waves, 4 units each
    const int grid = gw / 4;                 // 2048 blocks (4 waves/block)
    chol_from_z_kernel<<<grid, 256, 0, stream>>>(z, out, gw);
}